// Round 1
// baseline (448.478 us; speedup 1.0000x reference)
//
#include <hip/hip_runtime.h>
#include <hip/hip_bf16.h>

#define NDIM 128
#define NNODES 50000
#define CAP 64   // max in-degree slots; degrees ~ Poisson(16), max ~40 for this size

// ---------------------------------------------------------------------------
// Build per-dst bucket lists: cnt[d] = in-degree (excl self-loop),
// bucket[d*CAP + j] = j-th source node of an edge into d.
// ---------------------------------------------------------------------------
__global__ __launch_bounds__(256) void k_build(const int* __restrict__ src,
                                               const int* __restrict__ dst,
                                               int* __restrict__ cnt,
                                               int* __restrict__ bucket, int E) {
    int e = blockIdx.x * 256 + threadIdx.x;
    if (e >= E) return;
    int d = dst[e];
    int p = atomicAdd(&cnt[d], 1);
    if (p < CAP) bucket[(long)d * CAP + p] = src[e];
}

// dinv[i] = rsqrt(deg_in + 1)   (self-loop included)
__global__ __launch_bounds__(256) void k_dinv(const int* __restrict__ cnt,
                                              float* __restrict__ dinv, int n) {
    int i = blockIdx.x * 256 + threadIdx.x;
    if (i < n) dinv[i] = rsqrtf((float)cnt[i] + 1.0f);
}

// ---------------------------------------------------------------------------
// H = X @ W   (f32, W staged in LDS; 16 nodes/block, 4 per wave, 2 cols/lane)
// ---------------------------------------------------------------------------
__global__ __launch_bounds__(256) void k_gemm(const float* __restrict__ X,
                                              const float* __restrict__ W,
                                              float* __restrict__ H) {
    __shared__ float sW[NDIM * NDIM];
    for (int i = threadIdx.x; i < NDIM * NDIM / 4; i += 256)
        ((float4*)sW)[i] = ((const float4*)W)[i];
    __syncthreads();

    const int wave = threadIdx.x >> 6, lane = threadIdx.x & 63;
    const int n0 = blockIdx.x * 16 + wave * 4;     // 50000 = 3125 * 16, exact
    const float* x0 = X + (long)n0 * NDIM;

    float acc[4][2] = {{0.f,0.f},{0.f,0.f},{0.f,0.f},{0.f,0.f}};
    for (int k = 0; k < NDIM; k += 4) {
        float4 xr[4];
        xr[0] = *(const float4*)(x0 + 0 * NDIM + k);
        xr[1] = *(const float4*)(x0 + 1 * NDIM + k);
        xr[2] = *(const float4*)(x0 + 2 * NDIM + k);
        xr[3] = *(const float4*)(x0 + 3 * NDIM + k);
#pragma unroll
        for (int kk = 0; kk < 4; kk++) {
            const float w0 = sW[(k + kk) * NDIM + lane];
            const float w1 = sW[(k + kk) * NDIM + lane + 64];
#pragma unroll
            for (int r = 0; r < 4; r++) {
                const float xv = ((const float*)&xr[r])[kk];
                acc[r][0] = fmaf(xv, w0, acc[r][0]);
                acc[r][1] = fmaf(xv, w1, acc[r][1]);
            }
        }
    }
#pragma unroll
    for (int r = 0; r < 4; r++) {
        H[(long)(n0 + r) * NDIM + lane]      = acc[r][0];
        H[(long)(n0 + r) * NDIM + lane + 64] = acc[r][1];
    }
}

// ---------------------------------------------------------------------------
// Fused: agg = sum_{e into node} dinv[s]*dinv[d]*h[s] + dinv[d]^2*h[d] + bias
//        out = relu(LayerNorm(agg)*lnw + lnb) + residual
// One wave per node; lane holds dims [2*lane, 2*lane+1].
// ---------------------------------------------------------------------------
__global__ __launch_bounds__(256) void k_agg(const float* __restrict__ h,
                                             const float* __restrict__ xres,
                                             const int* __restrict__ bucket,
                                             const int* __restrict__ cnt,
                                             const float* __restrict__ dinv,
                                             const float* __restrict__ bias,
                                             const float* __restrict__ lnw,
                                             const float* __restrict__ lnb,
                                             float* __restrict__ out, int n) {
    const int wave = threadIdx.x >> 6, lane = threadIdx.x & 63;
    const int node = blockIdx.x * 4 + wave;
    if (node >= n) return;

    int c = cnt[node];
    if (c > CAP) c = CAP;
    const float dv = dinv[node];
    const int d0 = lane * 2;

    // self-loop term
    float2 hv = *(const float2*)(h + (long)node * NDIM + d0);
    float ax = dv * dv * hv.x, ay = dv * dv * hv.y;

    const int* bk = bucket + (long)node * CAP;
    for (int j = 0; j < c; j++) {
        int s = bk[j];
        float nrm = dv * dinv[s];
        float2 sv = *(const float2*)(h + (long)s * NDIM + d0);
        ax = fmaf(nrm, sv.x, ax);
        ay = fmaf(nrm, sv.y, ay);
    }

    float2 bb = *(const float2*)(bias + d0);
    float v0 = ax + bb.x, v1 = ay + bb.y;

    // LayerNorm over 128 dims held across the wave (2 per lane)
    float s = v0 + v1;
    for (int o = 32; o; o >>= 1) s += __shfl_xor(s, o);
    const float mu = s * (1.0f / 128.0f);
    float e0 = v0 - mu, e1 = v1 - mu;
    float q = e0 * e0 + e1 * e1;
    for (int o = 32; o; o >>= 1) q += __shfl_xor(q, o);
    const float rinv = rsqrtf(q * (1.0f / 128.0f) + 1e-5f);

    float2 wv = *(const float2*)(lnw + d0);
    float2 bv = *(const float2*)(lnb + d0);
    float2 rv = *(const float2*)(xres + (long)node * NDIM + d0);
    float o0 = fmaxf(fmaf(e0 * rinv, wv.x, bv.x), 0.0f) + rv.x;
    float o1 = fmaxf(fmaf(e1 * rinv, wv.y, bv.y), 0.0f) + rv.y;
    *(float2*)(out + (long)node * NDIM + d0) = make_float2(o0, o1);
}

extern "C" void kernel_launch(void* const* d_in, const int* in_sizes, int n_in,
                              void* d_out, int out_size, void* d_ws, size_t ws_size,
                              hipStream_t stream) {
    const float* x    = (const float*)d_in[0];
    const int*   ei   = (const int*)d_in[1];
    const float* W0   = (const float*)d_in[2];
    const float* b0   = (const float*)d_in[3];
    const float* W1   = (const float*)d_in[4];
    const float* b1   = (const float*)d_in[5];
    const float* ln0w = (const float*)d_in[6];
    const float* ln0b = (const float*)d_in[7];
    const float* ln1w = (const float*)d_in[8];
    const float* ln1b = (const float*)d_in[9];
    float* out = (float*)d_out;

    const int E = in_sizes[1] / 2;
    const int* src = ei;
    const int* dst = ei + E;

    char* ws = (char*)d_ws;
    size_t o = 0;
    int*   cnt    = (int*)(ws + o);  o += (size_t)50048 * 4;
    float* dinv   = (float*)(ws + o); o += (size_t)50048 * 4;
    int*   bucket = (int*)(ws + o);  o += (size_t)NNODES * CAP * 4;
    float* h      = (float*)(ws + o); o += (size_t)NNODES * NDIM * 4;
    float* xmid   = (float*)(ws + o); o += (size_t)NNODES * NDIM * 4;

    hipMemsetAsync(cnt, 0, NNODES * sizeof(int), stream);
    k_build<<<(E + 255) / 256, 256, 0, stream>>>(src, dst, cnt, bucket, E);
    k_dinv<<<(NNODES + 255) / 256, 256, 0, stream>>>(cnt, dinv, NNODES);

    // layer 0
    k_gemm<<<NNODES / 16, 256, 0, stream>>>(x, W0, h);
    k_agg<<<(NNODES + 3) / 4, 256, 0, stream>>>(h, x, bucket, cnt, dinv, b0,
                                                ln0w, ln0b, xmid, NNODES);
    // layer 1
    k_gemm<<<NNODES / 16, 256, 0, stream>>>(xmid, W1, h);
    k_agg<<<(NNODES + 3) / 4, 256, 0, stream>>>(h, xmid, bucket, cnt, dinv, b1,
                                                ln1w, ln1b, out, NNODES);
}

// Round 2
// 296.010 us; speedup vs baseline: 1.5151x; 1.5151x over previous
//
#include <hip/hip_runtime.h>
#include <hip/hip_bf16.h>

#define NDIM 128
#define NNODES 50000
#define CAP 64   // max in-degree slots; Poisson(16) tail => P(deg>64) ~ 0

typedef short bf16x8 __attribute__((ext_vector_type(8)));
typedef float f32x4 __attribute__((ext_vector_type(4)));

__device__ __forceinline__ unsigned short f2bf(float f) {
    unsigned u = __builtin_bit_cast(unsigned, f);
    unsigned r = (u + 0x7FFF + ((u >> 16) & 1)) >> 16;   // RNE
    return (unsigned short)r;
}
__device__ __forceinline__ float bf2f(unsigned short u) {
    return __builtin_bit_cast(float, (unsigned)u << 16);
}

// ---------------------------------------------------------------------------
// Bucket build: cnt[d] = in-degree (excl self-loop), bucket[d*CAP+j] = src
// ---------------------------------------------------------------------------
__global__ __launch_bounds__(256) void k_build(const int* __restrict__ src,
                                               const int* __restrict__ dst,
                                               int* __restrict__ cnt,
                                               int* __restrict__ bucket, int E) {
    int e = blockIdx.x * 256 + threadIdx.x;
    if (e >= E) return;
    int d = dst[e];
    int p = atomicAdd(&cnt[d], 1);
    if (p < CAP) bucket[(long)d * CAP + p] = src[e];
}

__global__ __launch_bounds__(256) void k_dinv(const int* __restrict__ cnt,
                                              float* __restrict__ dinv, int n) {
    int i = blockIdx.x * 256 + threadIdx.x;
    if (i < n) dinv[i] = rsqrtf((float)cnt[i] + 1.0f);
}

// Transpose + bf16-convert both weight matrices once: Wt[c][k] = bf16(W[k][c])
__global__ __launch_bounds__(256) void k_prep(const float* __restrict__ W0,
                                              const float* __restrict__ W1,
                                              unsigned short* __restrict__ Wt0,
                                              unsigned short* __restrict__ Wt1) {
    int t = blockIdx.x * 256 + threadIdx.x;   // 16384 threads
    int k = t >> 7, c = t & 127;
    Wt0[c * NDIM + k] = f2bf(W0[k * NDIM + c]);
    Wt1[c * NDIM + k] = f2bf(W1[k * NDIM + c]);
}

// ---------------------------------------------------------------------------
// Hb = bf16( X @ W )  via mfma_f32_16x16x32_bf16.
// 64 nodes/block, 4 waves, each wave: 16 nodes x 128 cols (8 col-tiles).
// LDS: sX bf16 [64][128] (16KB) + sWt bf16 [128][128] (32KB), both with
// XOR swizzle b ^= ((b>>8)&7)<<4 (256-B rows) to kill fragment-read conflicts.
// ---------------------------------------------------------------------------
#define SWZ(b) ((b) ^ ((((b) >> 8) & 7) << 4))

__global__ __launch_bounds__(256) void k_gemm(const float* __restrict__ X,
                                              const unsigned short* __restrict__ Wtb,
                                              unsigned short* __restrict__ Hb,
                                              int n) {
    __shared__ char sMem[16384 + 32768];   // sX | sWt
    // stage Wt: linear 16-B chunks -> swizzled LDS
    {
        const uint4* srcp = (const uint4*)Wtb;
        for (int i = threadIdx.x; i < 2048; i += 256) {
            int b = i * 16;
            *(uint4*)(sMem + 16384 + SWZ(b)) = srcp[i];
        }
    }
    // stage X tile: f32 -> bf16, 4 elems per 8-B write
    {
        int base = blockIdx.x * 64;
        for (int i = threadIdx.x; i < 2048; i += 256) {   // 8192 elems / 4
            int row = i >> 5;
            int col4 = (i & 31) * 4;
            ushort4 v = {0, 0, 0, 0};
            if (base + row < n) {
                float4 f = *(const float4*)(X + (size_t)(base + row) * NDIM + col4);
                v.x = f2bf(f.x); v.y = f2bf(f.y); v.z = f2bf(f.z); v.w = f2bf(f.w);
            }
            int b = row * 256 + col4 * 2;
            *(ushort4*)(sMem + SWZ(b)) = v;
        }
    }
    __syncthreads();

    const int wave = threadIdx.x >> 6, lane = threadIdx.x & 63;
    const int r16 = lane & 15, hi = lane >> 4;

    bf16x8 a[4];
    const int arow = wave * 16 + r16;
#pragma unroll
    for (int kc = 0; kc < 4; kc++) {
        int b = arow * 256 + kc * 64 + hi * 16;
        a[kc] = *(const bf16x8*)(sMem + SWZ(b));
    }

    const int nodeb = blockIdx.x * 64 + wave * 16;
#pragma unroll
    for (int ct = 0; ct < 8; ct++) {
        f32x4 acc = {0.f, 0.f, 0.f, 0.f};
        const int brow = ct * 16 + r16;
#pragma unroll
        for (int kc = 0; kc < 4; kc++) {
            int b = brow * 256 + kc * 64 + hi * 16;
            bf16x8 bw = *(const bf16x8*)(sMem + 16384 + SWZ(b));
            acc = __builtin_amdgcn_mfma_f32_16x16x32_bf16(a[kc], bw, acc, 0, 0, 0);
        }
#pragma unroll
        for (int r = 0; r < 4; r++) {
            int node = nodeb + hi * 4 + r;   // D: row=(lane>>4)*4+r, col=ct*16+(lane&15)
            if (node < n) Hb[(size_t)node * NDIM + ct * 16 + r16] = f2bf(acc[r]);
        }
    }
}

// ---------------------------------------------------------------------------
// Fused: agg = sum_{e->node} dinv[s]*dinv[d]*h[s] + dinv[d]^2*h[node] + bias
//        out = relu(LN(agg)*lnw + lnb) + residual        (h is bf16)
// One wave per node; lane holds dims [2*lane, 2*lane+1].
// ---------------------------------------------------------------------------
__global__ __launch_bounds__(256) void k_agg(const unsigned short* __restrict__ hb,
                                             const float* __restrict__ xres,
                                             const int* __restrict__ bucket,
                                             const int* __restrict__ cnt,
                                             const float* __restrict__ dinv,
                                             const float* __restrict__ bias,
                                             const float* __restrict__ lnw,
                                             const float* __restrict__ lnb,
                                             float* __restrict__ out, int n) {
    const int wave = threadIdx.x >> 6, lane = threadIdx.x & 63;
    const int node = blockIdx.x * 4 + wave;
    if (node >= n) return;

    int c = cnt[node];
    if (c > CAP) c = CAP;
    const float dv = dinv[node];
    const int d0 = lane * 2;

    // preload neighbor ids + norms into lanes (CAP == wave size)
    const int* bk = bucket + (long)node * CAP;
    int sj = 0;
    float nj = 0.f;
    if (lane < c) { sj = bk[lane]; nj = dv * dinv[sj]; }

    // self-loop term
    ushort2 hv = *(const ushort2*)(hb + (size_t)node * NDIM + d0);
    float ax = dv * dv * bf2f(hv.x), ay = dv * dv * bf2f(hv.y);

    for (int j = 0; j < c; j++) {
        int s = __shfl(sj, j);
        float nrm = __shfl(nj, j);
        ushort2 sv = *(const ushort2*)(hb + (size_t)s * NDIM + d0);
        ax = fmaf(nrm, bf2f(sv.x), ax);
        ay = fmaf(nrm, bf2f(sv.y), ay);
    }

    float2 bb = *(const float2*)(bias + d0);
    float v0 = ax + bb.x, v1 = ay + bb.y;

    float s = v0 + v1;
    for (int o = 32; o; o >>= 1) s += __shfl_xor(s, o);
    const float mu = s * (1.0f / 128.0f);
    float e0 = v0 - mu, e1 = v1 - mu;
    float q = e0 * e0 + e1 * e1;
    for (int o = 32; o; o >>= 1) q += __shfl_xor(q, o);
    const float rinv = rsqrtf(q * (1.0f / 128.0f) + 1e-5f);

    float2 wv = *(const float2*)(lnw + d0);
    float2 bv = *(const float2*)(lnb + d0);
    float2 rv = *(const float2*)(xres + (size_t)node * NDIM + d0);
    float o0 = fmaxf(fmaf(e0 * rinv, wv.x, bv.x), 0.0f) + rv.x;
    float o1 = fmaxf(fmaf(e1 * rinv, wv.y, bv.y), 0.0f) + rv.y;
    *(float2*)(out + (size_t)node * NDIM + d0) = make_float2(o0, o1);
}

extern "C" void kernel_launch(void* const* d_in, const int* in_sizes, int n_in,
                              void* d_out, int out_size, void* d_ws, size_t ws_size,
                              hipStream_t stream) {
    const float* x    = (const float*)d_in[0];
    const int*   ei   = (const int*)d_in[1];
    const float* W0   = (const float*)d_in[2];
    const float* b0   = (const float*)d_in[3];
    const float* W1   = (const float*)d_in[4];
    const float* b1   = (const float*)d_in[5];
    const float* ln0w = (const float*)d_in[6];
    const float* ln0b = (const float*)d_in[7];
    const float* ln1w = (const float*)d_in[8];
    const float* ln1b = (const float*)d_in[9];
    float* out = (float*)d_out;

    const int E = in_sizes[1] / 2;
    const int* src = ei;
    const int* dst = ei + E;

    char* ws = (char*)d_ws;
    size_t o = 0;
    int*   cnt    = (int*)(ws + o);            o += (size_t)50048 * 4;
    float* dinv   = (float*)(ws + o);          o += (size_t)50048 * 4;
    int*   bucket = (int*)(ws + o);            o += (size_t)NNODES * CAP * 4;
    unsigned short* hb = (unsigned short*)(ws + o); o += (size_t)NNODES * NDIM * 2;
    float* xmid   = (float*)(ws + o);          o += (size_t)NNODES * NDIM * 4;
    unsigned short* Wt0 = (unsigned short*)(ws + o); o += (size_t)NDIM * NDIM * 2;
    unsigned short* Wt1 = (unsigned short*)(ws + o); o += (size_t)NDIM * NDIM * 2;

    hipMemsetAsync(cnt, 0, NNODES * sizeof(int), stream);
    k_build<<<(E + 255) / 256, 256, 0, stream>>>(src, dst, cnt, bucket, E);
    k_dinv<<<(NNODES + 255) / 256, 256, 0, stream>>>(cnt, dinv, NNODES);
    k_prep<<<64, 256, 0, stream>>>(W0, W1, Wt0, Wt1);

    const int gemm_grid = (NNODES + 63) / 64;   // 782
    // layer 0
    k_gemm<<<gemm_grid, 256, 0, stream>>>(x, Wt0, hb, NNODES);
    k_agg<<<NNODES / 4, 256, 0, stream>>>(hb, x, bucket, cnt, dinv, b0,
                                          ln0w, ln0b, xmid, NNODES);
    // layer 1
    k_gemm<<<gemm_grid, 256, 0, stream>>>(xmid, Wt1, hb, NNODES);
    k_agg<<<NNODES / 4, 256, 0, stream>>>(hb, xmid, bucket, cnt, dinv, b1,
                                          ln1w, ln1b, out, NNODES);
}

// Round 3
// 229.578 us; speedup vs baseline: 1.9535x; 1.2894x over previous
//
#include <hip/hip_runtime.h>
#include <hip/hip_bf16.h>

#define NDIM 128
#define NNODES 50000
#define CAP 64   // max in-degree slots; Poisson(16) => P(deg>64) ~ 0 (verified: r2 passed)
#define SWZ(b) ((b) ^ ((((b) >> 8) & 7) << 4))

typedef short bf16x8 __attribute__((ext_vector_type(8)));
typedef float f32x4 __attribute__((ext_vector_type(4)));

__device__ __forceinline__ unsigned short f2bf(float f) {
    unsigned u = __builtin_bit_cast(unsigned, f);
    unsigned r = (u + 0x7FFF + ((u >> 16) & 1)) >> 16;   // RNE
    return (unsigned short)r;
}
__device__ __forceinline__ float bf2f(unsigned short u) {
    return __builtin_bit_cast(float, (unsigned)u << 16);
}

__device__ __forceinline__ void gl_lds16(const void* g, void* l) {
    __builtin_amdgcn_global_load_lds(
        (const __attribute__((address_space(1))) unsigned int*)g,
        (__attribute__((address_space(3))) unsigned int*)l, 16, 0, 0);
}

// ---------------------------------------------------------------------------
// Bucket build: cnt[d] = in-degree (excl self-loop), bucket[d*CAP+j] = src
// ---------------------------------------------------------------------------
__global__ __launch_bounds__(256) void k_build(const int* __restrict__ src,
                                               const int* __restrict__ dst,
                                               int* __restrict__ cnt,
                                               int* __restrict__ bucket, int E) {
    int e = blockIdx.x * 256 + threadIdx.x;
    if (e >= E) return;
    int d = dst[e];
    int p = atomicAdd(&cnt[d], 1);
    if (p < CAP) bucket[(long)d * CAP + p] = src[e];
}

// ---------------------------------------------------------------------------
// Fused prep: dinv[i] = rsqrt(cnt+1)  AND  W0/W1 -> bf16, transposed,
// PRE-SWIZZLED in global so gemm can global_load_lds linearly and read
// with SWZ (SWZ is an involution: store element b at SWZ(b)).
// ---------------------------------------------------------------------------
__global__ __launch_bounds__(256) void k_prep(const int* __restrict__ cnt,
                                              float* __restrict__ dinv,
                                              const float* __restrict__ W0,
                                              const float* __restrict__ W1,
                                              unsigned short* __restrict__ Ws0,
                                              unsigned short* __restrict__ Ws1) {
    int b = blockIdx.x;
    if (b < 196) {
        int i = b * 256 + threadIdx.x;
        if (i < NNODES) dinv[i] = rsqrtf((float)cnt[i] + 1.0f);
    } else {
        int t = (b - 196) * 256 + threadIdx.x;    // 0..32767
        const float* W = (t >> 14) ? W1 : W0;
        unsigned short* Wd = (t >> 14) ? Ws1 : Ws0;
        int e = t & 16383;
        int k = e >> 7, c = e & 127;
        int byteb = c * 256 + k * 2;              // logical: Wt[c][k], 256-B rows
        Wd[SWZ(byteb) >> 1] = f2bf(W[k * NDIM + c]);
    }
}

// ---------------------------------------------------------------------------
// Hb[row] = bf16( dinv[row] * (X @ W)[row] )   via mfma_f32_16x16x32_bf16.
// 64 nodes/block, 4 waves x 16 nodes x 128 cols. W: 32KB LDS via
// global_load_lds (source pre-swizzled). A-fragments: global->reg, cvt bf16.
// ---------------------------------------------------------------------------
__global__ __launch_bounds__(256) void k_gemm(const float* __restrict__ X,
                                              const unsigned short* __restrict__ Wsw,
                                              const float* __restrict__ dinv,
                                              unsigned short* __restrict__ Hb,
                                              int n) {
    __shared__ char sW[32768];
    const int wave = threadIdx.x >> 6, lane = threadIdx.x & 63;
    {
        const char* g = (const char*)Wsw;
#pragma unroll
        for (int i = 0; i < 8; i++) {
            int off = (i * 4 + wave) * 1024 + lane * 16;
            gl_lds16(g + off, sW + off);
        }
    }
    const int r16 = lane & 15, hi = lane >> 4;
    const int nodeb = blockIdx.x * 64 + wave * 16;
    int arow = nodeb + r16; if (arow > n - 1) arow = n - 1;

    bf16x8 a[4];
    const float* xp = X + (size_t)arow * NDIM + hi * 8;
#pragma unroll
    for (int kc = 0; kc < 4; kc++) {
        float4 f0 = *(const float4*)(xp + kc * 32);
        float4 f1 = *(const float4*)(xp + kc * 32 + 4);
        bf16x8 v;
        v[0] = f2bf(f0.x); v[1] = f2bf(f0.y); v[2] = f2bf(f0.z); v[3] = f2bf(f0.w);
        v[4] = f2bf(f1.x); v[5] = f2bf(f1.y); v[6] = f2bf(f1.z); v[7] = f2bf(f1.w);
        a[kc] = v;
    }
    float dr[4];
#pragma unroll
    for (int r = 0; r < 4; r++) {
        int row = nodeb + hi * 4 + r;
        dr[r] = dinv[row < n ? row : n - 1];
    }
    __syncthreads();   // drains vmcnt -> W staged

#pragma unroll
    for (int ct = 0; ct < 8; ct++) {
        f32x4 acc = {0.f, 0.f, 0.f, 0.f};
#pragma unroll
        for (int kc = 0; kc < 4; kc++) {
            int bb = (ct * 16 + r16) * 256 + kc * 64 + hi * 16;
            bf16x8 bw = *(const bf16x8*)(sW + SWZ(bb));
            acc = __builtin_amdgcn_mfma_f32_16x16x32_bf16(a[kc], bw, acc, 0, 0, 0);
        }
#pragma unroll
        for (int r = 0; r < 4; r++) {
            int row = nodeb + hi * 4 + r;   // D: row=(lane>>4)*4+r, col=ct*16+(lane&15)
            if (row < n)
                Hb[(size_t)row * NDIM + ct * 16 + r16] = f2bf(acc[r] * dr[r]);
        }
    }
}

// ---------------------------------------------------------------------------
// agg = dv * ( hb[node] + sum_{s in N(node)} hb[s] ) + bias    (hb pre-scaled)
// out = relu(LN(agg)*lnw + lnb) + xres
// 16 lanes/node, 8 dims/lane (16-B gathers), 4 nodes/wave, 16 nodes/block.
// ---------------------------------------------------------------------------
__global__ __launch_bounds__(256) void k_agg(const unsigned short* __restrict__ hb,
                                             const float* __restrict__ xres,
                                             const int* __restrict__ bucket,
                                             const int* __restrict__ cnt,
                                             const float* __restrict__ dinv,
                                             const float* __restrict__ bias,
                                             const float* __restrict__ lnw,
                                             const float* __restrict__ lnb,
                                             float* __restrict__ out) {
    const int tid = threadIdx.x;
    const int l16 = tid & 15;
    const int node = blockIdx.x * 16 + (tid >> 4);   // 50000 = 3125*16 exact
    const int d0 = l16 * 8;

    const float dv = dinv[node];
    int c = cnt[node]; if (c > CAP) c = CAP;

    float acc[8];
    {
        bf16x8 sv = *(const bf16x8*)(hb + (size_t)node * NDIM + d0);
#pragma unroll
        for (int t = 0; t < 8; t++) acc[t] = bf2f((unsigned short)sv[t]);
    }

    const int* bk = bucket + (size_t)node * CAP;
    int j = 0;
    for (; j + 4 <= c; j += 4) {
        int s0 = bk[j], s1 = bk[j + 1], s2 = bk[j + 2], s3 = bk[j + 3];
        bf16x8 r0 = *(const bf16x8*)(hb + (size_t)s0 * NDIM + d0);
        bf16x8 r1 = *(const bf16x8*)(hb + (size_t)s1 * NDIM + d0);
        bf16x8 r2 = *(const bf16x8*)(hb + (size_t)s2 * NDIM + d0);
        bf16x8 r3 = *(const bf16x8*)(hb + (size_t)s3 * NDIM + d0);
#pragma unroll
        for (int t = 0; t < 8; t++)
            acc[t] += (bf2f((unsigned short)r0[t]) + bf2f((unsigned short)r1[t]))
                    + (bf2f((unsigned short)r2[t]) + bf2f((unsigned short)r3[t]));
    }
    for (; j < c; j++) {
        int s = bk[j];
        bf16x8 r = *(const bf16x8*)(hb + (size_t)s * NDIM + d0);
#pragma unroll
        for (int t = 0; t < 8; t++) acc[t] += bf2f((unsigned short)r[t]);
    }

    float v[8];
    float4 bb0 = *(const float4*)(bias + d0);
    float4 bb1 = *(const float4*)(bias + d0 + 4);
    v[0] = fmaf(dv, acc[0], bb0.x); v[1] = fmaf(dv, acc[1], bb0.y);
    v[2] = fmaf(dv, acc[2], bb0.z); v[3] = fmaf(dv, acc[3], bb0.w);
    v[4] = fmaf(dv, acc[4], bb1.x); v[5] = fmaf(dv, acc[5], bb1.y);
    v[6] = fmaf(dv, acc[6], bb1.z); v[7] = fmaf(dv, acc[7], bb1.w);

    float s = 0.f;
#pragma unroll
    for (int t = 0; t < 8; t++) s += v[t];
#pragma unroll
    for (int o = 1; o < 16; o <<= 1) s += __shfl_xor(s, o);
    const float mu = s * (1.0f / 128.0f);

    float e[8], q = 0.f;
#pragma unroll
    for (int t = 0; t < 8; t++) { e[t] = v[t] - mu; q += e[t] * e[t]; }
#pragma unroll
    for (int o = 1; o < 16; o <<= 1) q += __shfl_xor(q, o);
    const float rinv = rsqrtf(q * (1.0f / 128.0f) + 1e-5f);

    float4 w0 = *(const float4*)(lnw + d0), w1 = *(const float4*)(lnw + d0 + 4);
    float4 lb0 = *(const float4*)(lnb + d0), lb1 = *(const float4*)(lnb + d0 + 4);
    float4 x0 = *(const float4*)(xres + (size_t)node * NDIM + d0);
    float4 x1 = *(const float4*)(xres + (size_t)node * NDIM + d0 + 4);

    float4 o0, o1;
    o0.x = fmaxf(fmaf(e[0] * rinv, w0.x, lb0.x), 0.f) + x0.x;
    o0.y = fmaxf(fmaf(e[1] * rinv, w0.y, lb0.y), 0.f) + x0.y;
    o0.z = fmaxf(fmaf(e[2] * rinv, w0.z, lb0.z), 0.f) + x0.z;
    o0.w = fmaxf(fmaf(e[3] * rinv, w0.w, lb0.w), 0.f) + x0.w;
    o1.x = fmaxf(fmaf(e[4] * rinv, w1.x, lb1.x), 0.f) + x1.x;
    o1.y = fmaxf(fmaf(e[5] * rinv, w1.y, lb1.y), 0.f) + x1.y;
    o1.z = fmaxf(fmaf(e[6] * rinv, w1.z, lb1.z), 0.f) + x1.z;
    o1.w = fmaxf(fmaf(e[7] * rinv, w1.w, lb1.w), 0.f) + x1.w;
    *(float4*)(out + (size_t)node * NDIM + d0) = o0;
    *(float4*)(out + (size_t)node * NDIM + d0 + 4) = o1;
}

extern "C" void kernel_launch(void* const* d_in, const int* in_sizes, int n_in,
                              void* d_out, int out_size, void* d_ws, size_t ws_size,
                              hipStream_t stream) {
    const float* x    = (const float*)d_in[0];
    const int*   ei   = (const int*)d_in[1];
    const float* W0   = (const float*)d_in[2];
    const float* b0   = (const float*)d_in[3];
    const float* W1   = (const float*)d_in[4];
    const float* b1   = (const float*)d_in[5];
    const float* ln0w = (const float*)d_in[6];
    const float* ln0b = (const float*)d_in[7];
    const float* ln1w = (const float*)d_in[8];
    const float* ln1b = (const float*)d_in[9];
    float* out = (float*)d_out;

    const int E = in_sizes[1] / 2;
    const int* src = ei;
    const int* dst = ei + E;

    char* ws = (char*)d_ws;
    size_t o = 0;
    int*   cnt    = (int*)(ws + o);                 o += (size_t)50048 * 4;
    float* dinv   = (float*)(ws + o);               o += (size_t)50048 * 4;
    int*   bucket = (int*)(ws + o);                 o += (size_t)NNODES * CAP * 4;
    unsigned short* hb = (unsigned short*)(ws + o); o += (size_t)NNODES * NDIM * 2;
    float* xmid   = (float*)(ws + o);               o += (size_t)NNODES * NDIM * 4;
    unsigned short* Ws0 = (unsigned short*)(ws + o); o += (size_t)NDIM * NDIM * 2;
    unsigned short* Ws1 = (unsigned short*)(ws + o); o += (size_t)NDIM * NDIM * 2;

    hipMemsetAsync(cnt, 0, NNODES * sizeof(int), stream);
    k_build<<<(E + 255) / 256, 256, 0, stream>>>(src, dst, cnt, bucket, E);
    k_prep<<<324, 256, 0, stream>>>(cnt, dinv, W0, W1, Ws0, Ws1);

    const int gemm_grid = (NNODES + 63) / 64;   // 782
    // layer 0
    k_gemm<<<gemm_grid, 256, 0, stream>>>(x, Ws0, dinv, hb, NNODES);
    k_agg<<<NNODES / 16, 256, 0, stream>>>(hb, x, bucket, cnt, dinv, b0,
                                           ln0w, ln0b, xmid);
    // layer 1
    k_gemm<<<gemm_grid, 256, 0, stream>>>(xmid, Ws1, dinv, hb, NNODES);
    k_agg<<<NNODES / 16, 256, 0, stream>>>(hb, xmid, bucket, cnt, dinv, b1,
                                           ln1w, ln1b, out);
}